// Round 4
// baseline (542.238 us; speedup 1.0000x reference)
//
#include <hip/hip_runtime.h>
#include <hip/hip_bf16.h>

// GraphSAGE 3-layer forward, MI355X. Round 4:
//  - CSR build reworked: bucketed 2-phase (distribute -> per-bucket LDS build).
//    Kills the 16x write amplification of the old atomic-scatter fill
//    (adj lines now written densely by a single block) and eliminates the
//    global histogram/scatter kernels.
//  - casts fused into one kernel.
//  - MFMA GEMM / batched-gather aggregation unchanged from R3.

typedef __attribute__((ext_vector_type(8))) short bf16x8;
typedef __attribute__((ext_vector_type(4))) float f32x4;

#define NPB 128            // nodes per bucket (bucket = dst >> 7)
#define BCAP 2560          // staged-edge capacity per bucket (mean 2048, sd 45 -> +11 sigma)

__device__ __forceinline__ unsigned short f2bf(float f) {
    unsigned int u = __builtin_bit_cast(unsigned int, f);
    u += 0x7fffu + ((u >> 16) & 1u);           // round-to-nearest-even
    return (unsigned short)(u >> 16);
}
__device__ __forceinline__ float bf2f(unsigned int bits16) {
    return __builtin_bit_cast(float, bits16 << 16);
}

// ---------------- CSR build: phase A (distribute to buckets) ----------------
// staging word: (dst & 127) << 16 | src   (src < 65536 since N = 50000)

__global__ void distribute_kernel(const int* __restrict__ dst, const int* __restrict__ srcv,
                                  int* __restrict__ cnt, unsigned int* __restrict__ staging,
                                  int E) {
    int e = blockIdx.x * 256 + threadIdx.x;
    if (e < E) {
        int d = dst[e];
        int s = srcv[e];
        int b = d >> 7;
        int p = atomicAdd(&cnt[b], 1);
        staging[(size_t)b * BCAP + p] = ((unsigned int)(d & (NPB - 1)) << 16) | (unsigned int)s;
    }
}

// ---------------- CSR build: bucket-base scan (1 block) ----------------

__global__ __launch_bounds__(512) void bucket_scan_kernel(const int* __restrict__ cnt,
                                                          int* __restrict__ base, int NB,
                                                          int* __restrict__ rowptr_last) {
    __shared__ int sh[512];
    int t = threadIdx.x;
    int v = (t < NB) ? cnt[t] : 0;
    sh[t] = v; __syncthreads();
    for (int off = 1; off < 512; off <<= 1) {
        int u = (t >= off) ? sh[t - off] : 0;
        __syncthreads();
        sh[t] += u;
        __syncthreads();
    }
    if (t < NB) base[t] = sh[t] - v;        // exclusive
    if (t == 511) *rowptr_last = sh[511];   // total == E
}

// ---------------- CSR build: phase B (per-bucket local build) ----------------
// One block per bucket: LDS histogram over its <=128 nodes, LDS scan, write
// row_ptr, then scatter adj via LDS cursors. All adj writes for this bucket
// land in a dense ~8KB window from one CU -> full-line writebacks.

__global__ __launch_bounds__(256) void build_kernel(const unsigned int* __restrict__ staging,
                                                    const int* __restrict__ cnt,
                                                    const int* __restrict__ base,
                                                    int* __restrict__ row_ptr,
                                                    int* __restrict__ adj, int N) {
    __shared__ int hist[NPB];   // histogram, then cursors
    __shared__ int scn[NPB];
    int b = blockIdx.x;
    int t = threadIdx.x;
    int n0 = b * NPB;
    int nb = N - n0; if (nb > NPB) nb = NPB;
    int ec = cnt[b];
    int bb = base[b];
    const unsigned int* st = staging + (size_t)b * BCAP;

    if (t < NPB) hist[t] = 0;
    __syncthreads();
    for (int i = t; i < ec; i += 256)
        atomicAdd(&hist[st[i] >> 16], 1);
    __syncthreads();

    int v = (t < NPB) ? hist[t] : 0;
    if (t < NPB) scn[t] = v;
    __syncthreads();
    for (int off = 1; off < NPB; off <<= 1) {
        int u = (t >= off && t < NPB) ? scn[t - off] : 0;
        __syncthreads();
        if (t < NPB) scn[t] += u;
        __syncthreads();
    }
    if (t < NPB) hist[t] = scn[t] - v;      // exclusive prefix -> cursor base
    if (t < nb) row_ptr[n0 + t] = bb + (scn[t] - v);
    __syncthreads();

    for (int i = t; i < ec; i += 256) {
        unsigned int pk = st[i];
        int p = atomicAdd(&hist[pk >> 16], 1);
        adj[bb + p] = (int)(pk & 0xffffu);
    }
}

// ---------------- fused casts: x (N x 128) + 6 weight tensors -> bf16 ----------------

__global__ void cast_all_kernel(const float* __restrict__ x,
                                const float* p0, const float* p1, const float* p2,
                                const float* p3, const float* p4, const float* p5,
                                unsigned short* __restrict__ xbf,
                                unsigned short* __restrict__ wbf, int xpairs) {
    int bid = blockIdx.x;
    int xblocks = (xpairs + 255) / 256;
    if (bid < xblocks) {
        int i = bid * 256 + threadIdx.x;
        if (i < xpairs) {
            float2 v = ((const float2*)x)[i];
            unsigned int p = (unsigned int)f2bf(v.x) | ((unsigned int)f2bf(v.y) << 16);
            ((unsigned int*)xbf)[i] = p;
        }
    } else {
        int w = (bid - xblocks) * 256 + threadIdx.x;      // pair index into wbf (40960 pairs)
        if (w < 40960) {
            const float* src;
            int local;
            if      (w < 8192)  { src = p0; local = w; }
            else if (w < 16384) { src = p1; local = w - 8192; }
            else if (w < 24576) { src = p2; local = w - 16384; }
            else if (w < 32768) { src = p3; local = w - 24576; }
            else if (w < 36864) { src = p4; local = w - 32768; }
            else                { src = p5; local = w - 36864; }
            float2 v = ((const float2*)src)[local];
            unsigned int p = (unsigned int)f2bf(v.x) | ((unsigned int)f2bf(v.y) << 16);
            ((unsigned int*)wbf)[w] = p;
        }
    }
}

// ---------------- MFMA GEMM (unchanged) ----------------

__global__ __launch_bounds__(256) void gemm_mfma_kernel(const unsigned short* __restrict__ H,
                                                        const unsigned short* __restrict__ Wl,
                                                        const unsigned short* __restrict__ Wr,
                                                        unsigned short* __restrict__ C,
                                                        int N, int ldC) {
    int wave = threadIdx.x >> 6;
    int lane = threadIdx.x & 63;
    int l15 = lane & 15, quad = lane >> 4;
    int y = blockIdx.y, half = gridDim.y >> 1;
    const unsigned short* W = (y < half) ? Wl : Wr;
    int wrow0 = (y < half ? y : y - half) * 64;
    int col0 = y * 64;
    int m0 = blockIdx.x * 128 + wave * 32;

    int r0 = m0 + l15;      if (r0 > N - 1) r0 = N - 1;
    int r1 = m0 + 16 + l15; if (r1 > N - 1) r1 = N - 1;
    const bf16x8* A0 = (const bf16x8*)(H + (size_t)r0 * 128);
    const bf16x8* A1 = (const bf16x8*)(H + (size_t)r1 * 128);

    f32x4 acc[2][4] = {};
#pragma unroll
    for (int ks = 0; ks < 4; ++ks) {
        int vidx = ks * 4 + quad;
        bf16x8 a0 = A0[vidx];
        bf16x8 a1 = A1[vidx];
#pragma unroll
        for (int j = 0; j < 4; ++j) {
            const bf16x8* B = (const bf16x8*)(W + (size_t)(wrow0 + j * 16 + l15) * 128);
            bf16x8 b = B[vidx];
            acc[0][j] = __builtin_amdgcn_mfma_f32_16x16x32_bf16(a0, b, acc[0][j], 0, 0, 0);
            acc[1][j] = __builtin_amdgcn_mfma_f32_16x16x32_bf16(a1, b, acc[1][j], 0, 0, 0);
        }
    }

#pragma unroll
    for (int i = 0; i < 2; ++i)
#pragma unroll
        for (int j = 0; j < 4; ++j)
#pragma unroll
            for (int r = 0; r < 4; ++r) {
                int row = m0 + i * 16 + quad * 4 + r;
                if (row < N) {
                    int col = col0 + j * 16 + l15;
                    C[(size_t)row * ldC + col] = f2bf(acc[i][j][r]);
                }
            }
}

// ---------------- Aggregation (layers 0,1): wave/node, batched gathers ----------------

__global__ __launch_bounds__(256) void agg_relu_kernel(const unsigned short* __restrict__ C,
                                                       const int* __restrict__ row_ptr,
                                                       const int* __restrict__ adj,
                                                       const float* __restrict__ bias,
                                                       unsigned short* __restrict__ hout, int N) {
    int node = (int)((blockIdx.x * blockDim.x + threadIdx.x) >> 6);
    int lane = threadIdx.x & 63;
    if (node >= N) return;
    int beg = row_ptr[node], end = row_ptr[node + 1];
    float sx0 = 0.f, sy0 = 0.f, sx1 = 0.f, sy1 = 0.f;
    float sx2 = 0.f, sy2 = 0.f, sx3 = 0.f, sy3 = 0.f;

    int e = beg;
    while (e < end) {
        int cnt = end - e; if (cnt > 64) cnt = 64;
        int ll = lane; if (ll > cnt - 1) ll = cnt - 1;
        int myidx = adj[e + ll];

        int i = 0;
        for (; i + 8 <= cnt; i += 8) {
            int s0 = __shfl(myidx, i + 0), s1 = __shfl(myidx, i + 1);
            int s2 = __shfl(myidx, i + 2), s3 = __shfl(myidx, i + 3);
            int s4 = __shfl(myidx, i + 4), s5 = __shfl(myidx, i + 5);
            int s6 = __shfl(myidx, i + 6), s7 = __shfl(myidx, i + 7);
            unsigned int v0 = ((const unsigned int*)(C + (size_t)s0 * 256))[lane];
            unsigned int v1 = ((const unsigned int*)(C + (size_t)s1 * 256))[lane];
            unsigned int v2 = ((const unsigned int*)(C + (size_t)s2 * 256))[lane];
            unsigned int v3 = ((const unsigned int*)(C + (size_t)s3 * 256))[lane];
            unsigned int v4 = ((const unsigned int*)(C + (size_t)s4 * 256))[lane];
            unsigned int v5 = ((const unsigned int*)(C + (size_t)s5 * 256))[lane];
            unsigned int v6 = ((const unsigned int*)(C + (size_t)s6 * 256))[lane];
            unsigned int v7 = ((const unsigned int*)(C + (size_t)s7 * 256))[lane];
            sx0 += bf2f(v0 & 0xffffu); sy0 += bf2f(v0 >> 16);
            sx1 += bf2f(v1 & 0xffffu); sy1 += bf2f(v1 >> 16);
            sx2 += bf2f(v2 & 0xffffu); sy2 += bf2f(v2 >> 16);
            sx3 += bf2f(v3 & 0xffffu); sy3 += bf2f(v3 >> 16);
            sx0 += bf2f(v4 & 0xffffu); sy0 += bf2f(v4 >> 16);
            sx1 += bf2f(v5 & 0xffffu); sy1 += bf2f(v5 >> 16);
            sx2 += bf2f(v6 & 0xffffu); sy2 += bf2f(v6 >> 16);
            sx3 += bf2f(v7 & 0xffffu); sy3 += bf2f(v7 >> 16);
        }
        if (i < cnt) {
            int rem = cnt - i, c1 = cnt - 1;
            int t0 = i, t1 = i + 1, t2 = i + 2, t3 = i + 3;
            int t4 = i + 4, t5 = i + 5, t6 = i + 6, t7 = i + 7;
            int s0 = __shfl(myidx, t0 > c1 ? c1 : t0), s1 = __shfl(myidx, t1 > c1 ? c1 : t1);
            int s2 = __shfl(myidx, t2 > c1 ? c1 : t2), s3 = __shfl(myidx, t3 > c1 ? c1 : t3);
            int s4 = __shfl(myidx, t4 > c1 ? c1 : t4), s5 = __shfl(myidx, t5 > c1 ? c1 : t5);
            int s6 = __shfl(myidx, t6 > c1 ? c1 : t6), s7 = __shfl(myidx, t7 > c1 ? c1 : t7);
            unsigned int v0 = ((const unsigned int*)(C + (size_t)s0 * 256))[lane];
            unsigned int v1 = ((const unsigned int*)(C + (size_t)s1 * 256))[lane];
            unsigned int v2 = ((const unsigned int*)(C + (size_t)s2 * 256))[lane];
            unsigned int v3 = ((const unsigned int*)(C + (size_t)s3 * 256))[lane];
            unsigned int v4 = ((const unsigned int*)(C + (size_t)s4 * 256))[lane];
            unsigned int v5 = ((const unsigned int*)(C + (size_t)s5 * 256))[lane];
            unsigned int v6 = ((const unsigned int*)(C + (size_t)s6 * 256))[lane];
            unsigned int v7 = ((const unsigned int*)(C + (size_t)s7 * 256))[lane];
            float m1 = rem > 1 ? 1.f : 0.f, m2 = rem > 2 ? 1.f : 0.f, m3 = rem > 3 ? 1.f : 0.f;
            float m4 = rem > 4 ? 1.f : 0.f, m5 = rem > 5 ? 1.f : 0.f, m6 = rem > 6 ? 1.f : 0.f;
            float m7 = rem > 7 ? 1.f : 0.f;
            sx0 += bf2f(v0 & 0xffffu);      sy0 += bf2f(v0 >> 16);
            sx1 += m1 * bf2f(v1 & 0xffffu); sy1 += m1 * bf2f(v1 >> 16);
            sx2 += m2 * bf2f(v2 & 0xffffu); sy2 += m2 * bf2f(v2 >> 16);
            sx3 += m3 * bf2f(v3 & 0xffffu); sy3 += m3 * bf2f(v3 >> 16);
            sx0 += m4 * bf2f(v4 & 0xffffu); sy0 += m4 * bf2f(v4 >> 16);
            sx1 += m5 * bf2f(v5 & 0xffffu); sy1 += m5 * bf2f(v5 >> 16);
            sx2 += m6 * bf2f(v6 & 0xffffu); sy2 += m6 * bf2f(v6 >> 16);
            sx3 += m7 * bf2f(v7 & 0xffffu); sy3 += m7 * bf2f(v7 >> 16);
        }
        e += cnt;
    }

    float sx = (sx0 + sx1) + (sx2 + sx3);
    float sy = (sy0 + sy1) + (sy2 + sy3);
    int deg = end - beg;
    float inv = 1.0f / (float)(deg > 1 ? deg : 1);
    float2 bb = ((const float2*)bias)[lane];
    unsigned int rv = ((const unsigned int*)(C + (size_t)node * 256))[64 + lane];
    float ox = fmaxf(sx * inv + bb.x + bf2f(rv & 0xffffu), 0.f);
    float oy = fmaxf(sy * inv + bb.y + bf2f(rv >> 16), 0.f);
    unsigned int p = (unsigned int)f2bf(ox) | ((unsigned int)f2bf(oy) << 16);
    ((unsigned int*)(hout + (size_t)node * 128))[lane] = p;
}

// ---------------- Final layer: batched gathers + fused log_softmax ----------------

__global__ __launch_bounds__(256) void final_kernel(const unsigned short* __restrict__ C,
                                                    const int* __restrict__ row_ptr,
                                                    const int* __restrict__ adj,
                                                    const float* __restrict__ bias,
                                                    float* __restrict__ out, int N) {
    int node = (int)((blockIdx.x * blockDim.x + threadIdx.x) >> 6);
    int lane = threadIdx.x & 63;
    if (node >= N) return;
    int beg = row_ptr[node], end = row_ptr[node + 1];
    float a0 = 0.f, a1 = 0.f, a2 = 0.f, a3 = 0.f;

    int e = beg;
    while (e < end) {
        int cnt = end - e; if (cnt > 64) cnt = 64;
        int ll = lane; if (ll > cnt - 1) ll = cnt - 1;
        int myidx = adj[e + ll];

        int i = 0;
        for (; i + 8 <= cnt; i += 8) {
            int s0 = __shfl(myidx, i + 0), s1 = __shfl(myidx, i + 1);
            int s2 = __shfl(myidx, i + 2), s3 = __shfl(myidx, i + 3);
            int s4 = __shfl(myidx, i + 4), s5 = __shfl(myidx, i + 5);
            int s6 = __shfl(myidx, i + 6), s7 = __shfl(myidx, i + 7);
            float v0 = bf2f((unsigned int)C[(size_t)s0 * 128 + lane]);
            float v1 = bf2f((unsigned int)C[(size_t)s1 * 128 + lane]);
            float v2 = bf2f((unsigned int)C[(size_t)s2 * 128 + lane]);
            float v3 = bf2f((unsigned int)C[(size_t)s3 * 128 + lane]);
            float v4 = bf2f((unsigned int)C[(size_t)s4 * 128 + lane]);
            float v5 = bf2f((unsigned int)C[(size_t)s5 * 128 + lane]);
            float v6 = bf2f((unsigned int)C[(size_t)s6 * 128 + lane]);
            float v7 = bf2f((unsigned int)C[(size_t)s7 * 128 + lane]);
            a0 += v0 + v4; a1 += v1 + v5; a2 += v2 + v6; a3 += v3 + v7;
        }
        if (i < cnt) {
            int rem = cnt - i, c1 = cnt - 1;
            int t;
            t = i + 0; int s0 = __shfl(myidx, t > c1 ? c1 : t);
            t = i + 1; int s1 = __shfl(myidx, t > c1 ? c1 : t);
            t = i + 2; int s2 = __shfl(myidx, t > c1 ? c1 : t);
            t = i + 3; int s3 = __shfl(myidx, t > c1 ? c1 : t);
            t = i + 4; int s4 = __shfl(myidx, t > c1 ? c1 : t);
            t = i + 5; int s5 = __shfl(myidx, t > c1 ? c1 : t);
            t = i + 6; int s6 = __shfl(myidx, t > c1 ? c1 : t);
            t = i + 7; int s7 = __shfl(myidx, t > c1 ? c1 : t);
            float v0 = bf2f((unsigned int)C[(size_t)s0 * 128 + lane]);
            float v1 = bf2f((unsigned int)C[(size_t)s1 * 128 + lane]);
            float v2 = bf2f((unsigned int)C[(size_t)s2 * 128 + lane]);
            float v3 = bf2f((unsigned int)C[(size_t)s3 * 128 + lane]);
            float v4 = bf2f((unsigned int)C[(size_t)s4 * 128 + lane]);
            float v5 = bf2f((unsigned int)C[(size_t)s5 * 128 + lane]);
            float v6 = bf2f((unsigned int)C[(size_t)s6 * 128 + lane]);
            float v7 = bf2f((unsigned int)C[(size_t)s7 * 128 + lane]);
            float m1 = rem > 1 ? 1.f : 0.f, m2 = rem > 2 ? 1.f : 0.f, m3 = rem > 3 ? 1.f : 0.f;
            float m4 = rem > 4 ? 1.f : 0.f, m5 = rem > 5 ? 1.f : 0.f, m6 = rem > 6 ? 1.f : 0.f;
            float m7 = rem > 7 ? 1.f : 0.f;
            a0 += v0 + m4 * v4; a1 += m1 * v1 + m5 * v5;
            a2 += m2 * v2 + m6 * v6; a3 += m3 * v3 + m7 * v7;
        }
        e += cnt;
    }

    float sum = (a0 + a1) + (a2 + a3);
    int deg = end - beg;
    float inv = 1.0f / (float)(deg > 1 ? deg : 1);
    float u = sum * inv + bias[lane] + bf2f((unsigned int)C[(size_t)node * 128 + 64 + lane]);

    float m = u;
#pragma unroll
    for (int off = 32; off > 0; off >>= 1) m = fmaxf(m, __shfl_xor(m, off));
    float ex = __expf(u - m);
    float se = ex;
#pragma unroll
    for (int off = 32; off > 0; off >>= 1) se += __shfl_xor(se, off);
    out[(size_t)node * 64 + lane] = (u - m) - __logf(se);
}

// ---------------- Launch ----------------

extern "C" void kernel_launch(void* const* d_in, const int* in_sizes, int n_in,
                              void* d_out, int out_size, void* d_ws, size_t ws_size,
                              hipStream_t stream) {
    const float* x   = (const float*)d_in[0];
    const int*   ei  = (const int*)d_in[1];
    const float* Wl0 = (const float*)d_in[2];
    const float* bl0 = (const float*)d_in[3];
    const float* Wr0 = (const float*)d_in[4];
    const float* Wl1 = (const float*)d_in[5];
    const float* bl1 = (const float*)d_in[6];
    const float* Wr1 = (const float*)d_in[7];
    const float* Wl2 = (const float*)d_in[8];
    const float* bl2 = (const float*)d_in[9];
    const float* Wr2 = (const float*)d_in[10];
    float* out = (float*)d_out;

    const int N  = in_sizes[0] / 128;   // 50000
    const int E  = in_sizes[1] / 2;     // 800000
    const int NB = (N + NPB - 1) / NPB; // 391 buckets

    char* ws = (char*)d_ws;
    auto alloc = [&](size_t bytes) {
        char* p = ws;
        ws += (bytes + 255) & ~(size_t)255;
        return p;
    };
    int*   row_ptr    = (int*)alloc((size_t)(N + 1) * 4);
    int*   adj        = (int*)alloc((size_t)E * 4);
    int*   bucketCnt  = (int*)alloc((size_t)NB * 4);
    int*   bucketBase = (int*)alloc((size_t)NB * 4);
    unsigned int* staging = (unsigned int*)alloc((size_t)NB * BCAP * 4);
    unsigned short* xbf = (unsigned short*)alloc((size_t)N * 128 * 2);
    unsigned short* wbf = (unsigned short*)alloc((size_t)81920 * 2);
    unsigned short* C   = (unsigned short*)alloc((size_t)N * 256 * 2);
    unsigned short* hA  = (unsigned short*)alloc((size_t)N * 128 * 2);
    unsigned short* hB  = (unsigned short*)alloc((size_t)N * 128 * 2);

    const int* dstp = ei;       // edge_index row 0 = dst
    const int* srcp = ei + E;   // edge_index row 1 = src

    // CSR build (bucketed 2-phase)
    hipMemsetAsync(bucketCnt, 0, (size_t)NB * 4, stream);
    distribute_kernel<<<(E + 255) / 256, 256, 0, stream>>>(dstp, srcp, bucketCnt, staging, E);
    bucket_scan_kernel<<<1, 512, 0, stream>>>(bucketCnt, bucketBase, NB, row_ptr + N);
    build_kernel<<<NB, 256, 0, stream>>>(staging, bucketCnt, bucketBase, row_ptr, adj, N);

    // fused casts
    int xpairs = N * 64;
    int castBlocks = (xpairs + 255) / 256 + 160;
    cast_all_kernel<<<castBlocks, 256, 0, stream>>>(x, Wl0, Wr0, Wl1, Wr1, Wl2, Wr2,
                                                    xbf, wbf, xpairs);
    unsigned short* wl0 = wbf;
    unsigned short* wr0 = wbf + 16384;
    unsigned short* wl1 = wbf + 32768;
    unsigned short* wr1 = wbf + 49152;
    unsigned short* wl2 = wbf + 65536;
    unsigned short* wr2 = wbf + 73728;

    dim3 blk(256);
    int gemmRows = (N + 127) / 128;
    int aggBlocks = (N * 64 + 255) / 256;

    // Layer 0
    gemm_mfma_kernel<<<dim3(gemmRows, 4), blk, 0, stream>>>(xbf, wl0, wr0, C, N, 256);
    agg_relu_kernel<<<aggBlocks, blk, 0, stream>>>(C, row_ptr, adj, bl0, hA, N);
    // Layer 1
    gemm_mfma_kernel<<<dim3(gemmRows, 4), blk, 0, stream>>>(hA, wl1, wr1, C, N, 256);
    agg_relu_kernel<<<aggBlocks, blk, 0, stream>>>(C, row_ptr, adj, bl1, hB, N);
    // Layer 2 + log_softmax
    gemm_mfma_kernel<<<dim3(gemmRows, 2), blk, 0, stream>>>(hB, wl2, wr2, C, N, 128);
    final_kernel<<<aggBlocks, blk, 0, stream>>>(C, row_ptr, adj, bl2, out, N);
}

// Round 5
// 276.039 us; speedup vs baseline: 1.9644x; 1.9644x over previous
//
#include <hip/hip_runtime.h>
#include <hip/hip_bf16.h>

// GraphSAGE 3-layer forward, MI355X. Round 5:
//  - distribute reworked as block-staged radix pass: LDS histogram + one
//    padded-line global atomic per (block,bucket) + bucket-sorted LDS staging
//    written out as contiguous runs. R4's 391-counter global atomics were
//    800k atomics on 25 lines @ ~8.8ns/same-line-atomic = 281us. Now 98
//    atomics/counter on 391 separate lines.
//  - bucket_scan/build (R4) kept; MFMA GEMM + batched-gather agg unchanged.

typedef __attribute__((ext_vector_type(8))) short bf16x8;
typedef __attribute__((ext_vector_type(4))) float f32x4;

#define NPB 128            // nodes per bucket (bucket = dst >> 7)
#define BCAP 2560          // per-bucket staging capacity (mean 2048, sd ~45)
#define EPB 8192           // edges per distribute block
#define EPT 32             // edges per thread (256 thr)
#define CPAD 16            // global counter stride in ints (64B line each)

__device__ __forceinline__ unsigned short f2bf(float f) {
    unsigned int u = __builtin_bit_cast(unsigned int, f);
    u += 0x7fffu + ((u >> 16) & 1u);           // round-to-nearest-even
    return (unsigned short)(u >> 16);
}
__device__ __forceinline__ float bf2f(unsigned int bits16) {
    return __builtin_bit_cast(float, bits16 << 16);
}

// ---------------- CSR phase A: block-staged distribute ----------------
// staging word: dst << 16 | src (both < 65536). bucket = word >> 23 (= dst>>7).

__global__ __launch_bounds__(256) void distribute_kernel(const int* __restrict__ dst,
                                                         const int* __restrict__ srcv,
                                                         int* __restrict__ gcnt,
                                                         unsigned int* __restrict__ staging,
                                                         int E, int NBc) {
    __shared__ unsigned int stage[EPB];      // bucket-sorted edges (32KB)
    __shared__ int hist[400];                // histogram, then LDS cursor
    __shared__ int lstart[400];              // exclusive prefix (incl. sentinel bucket)
    __shared__ int gbase[400];               // reserved global base per bucket
    __shared__ int scanbuf[256];
    int t = threadIdx.x;
    int e0 = blockIdx.x * EPB;
    unsigned int w[EPT];

    for (int b = t; b < NBc + 1; b += 256) hist[b] = 0;
    __syncthreads();

#pragma unroll
    for (int i = 0; i < EPT; ++i) {
        int e = e0 + i * 256 + t;            // coalesced
        unsigned int word = 0xFFFFFFFFu;     // sentinel -> bucket NBc
        if (e < E) word = ((unsigned int)dst[e] << 16) | (unsigned int)srcv[e];
        w[i] = word;
        int b = (int)(word >> 23); if (b > NBc) b = NBc;
        atomicAdd(&hist[b], 1);
    }
    __syncthreads();

    // exclusive scan over NBc+1 entries (2 per thread, Hillis-Steele on pairs)
    int b0 = 2 * t, b1 = 2 * t + 1;
    int h0 = (b0 <= NBc) ? hist[b0] : 0;
    int h1 = (b1 <= NBc) ? hist[b1] : 0;
    int pair = h0 + h1;
    scanbuf[t] = pair;
    __syncthreads();
    for (int off = 1; off < 256; off <<= 1) {
        int v = (t >= off) ? scanbuf[t - off] : 0;
        __syncthreads();
        scanbuf[t] += v;
        __syncthreads();
    }
    int excl = scanbuf[t] - pair;
    if (b0 <= NBc) lstart[b0] = excl;
    if (b1 <= NBc) lstart[b1] = excl + h0;
    __syncthreads();

    // one padded-line global atomic per non-empty bucket
    for (int b = t; b < NBc; b += 256) {
        int h = hist[b];
        gbase[b] = h ? atomicAdd(&gcnt[b * CPAD], h) : 0;
    }
    for (int b = t; b < NBc + 1; b += 256) hist[b] = lstart[b];   // -> LDS cursors
    __syncthreads();

#pragma unroll
    for (int i = 0; i < EPT; ++i) {
        unsigned int word = w[i];
        int b = (int)(word >> 23); if (b > NBc) b = NBc;
        int p = atomicAdd(&hist[b], 1);
        stage[p] = word;
    }
    __syncthreads();

    int total = lstart[NBc];                 // valid edges in this block
    for (int i = t; i < total; i += 256) {   // contiguous runs per bucket
        unsigned int word = stage[i];
        int b = (int)(word >> 23);
        int gpos = gbase[b] + (i - lstart[b]);
        staging[(size_t)b * BCAP + gpos] = word;
    }
}

// ---------------- CSR: bucket-base scan (1 block) ----------------

__global__ __launch_bounds__(512) void bucket_scan_kernel(const int* __restrict__ gcnt,
                                                          int* __restrict__ base, int NBc,
                                                          int* __restrict__ rowptr_last) {
    __shared__ int sh[512];
    int t = threadIdx.x;
    int v = (t < NBc) ? gcnt[t * CPAD] : 0;
    sh[t] = v; __syncthreads();
    for (int off = 1; off < 512; off <<= 1) {
        int u = (t >= off) ? sh[t - off] : 0;
        __syncthreads();
        sh[t] += u;
        __syncthreads();
    }
    if (t < NBc) base[t] = sh[t] - v;       // exclusive
    if (t == 511) *rowptr_last = sh[511];   // total == E
}

// ---------------- CSR phase B: per-bucket local build ----------------

__global__ __launch_bounds__(256) void build_kernel(const unsigned int* __restrict__ staging,
                                                    const int* __restrict__ gcnt,
                                                    const int* __restrict__ base,
                                                    int* __restrict__ row_ptr,
                                                    int* __restrict__ adj, int N) {
    __shared__ int hist[NPB];   // histogram, then cursors
    __shared__ int scn[NPB];
    int b = blockIdx.x;
    int t = threadIdx.x;
    int n0 = b * NPB;
    int nb = N - n0; if (nb > NPB) nb = NPB;
    int ec = gcnt[b * CPAD];
    int bb = base[b];
    const unsigned int* st = staging + (size_t)b * BCAP;

    if (t < NPB) hist[t] = 0;
    __syncthreads();
    for (int i = t; i < ec; i += 256)
        atomicAdd(&hist[(st[i] >> 16) & (NPB - 1)], 1);
    __syncthreads();

    int v = (t < NPB) ? hist[t] : 0;
    if (t < NPB) scn[t] = v;
    __syncthreads();
    for (int off = 1; off < NPB; off <<= 1) {
        int u = (t >= off && t < NPB) ? scn[t - off] : 0;
        __syncthreads();
        if (t < NPB) scn[t] += u;
        __syncthreads();
    }
    if (t < NPB) hist[t] = scn[t] - v;      // exclusive prefix -> cursor base
    if (t < nb) row_ptr[n0 + t] = bb + (scn[t] - v);
    __syncthreads();

    for (int i = t; i < ec; i += 256) {
        unsigned int pk = st[i];
        int p = atomicAdd(&hist[(pk >> 16) & (NPB - 1)], 1);
        adj[bb + p] = (int)(pk & 0xffffu);
    }
}

// ---------------- fused casts: x (N x 128) + 6 weight tensors -> bf16 ----------------

__global__ void cast_all_kernel(const float* __restrict__ x,
                                const float* p0, const float* p1, const float* p2,
                                const float* p3, const float* p4, const float* p5,
                                unsigned short* __restrict__ xbf,
                                unsigned short* __restrict__ wbf, int xpairs) {
    int bid = blockIdx.x;
    int xblocks = (xpairs + 255) / 256;
    if (bid < xblocks) {
        int i = bid * 256 + threadIdx.x;
        if (i < xpairs) {
            float2 v = ((const float2*)x)[i];
            unsigned int p = (unsigned int)f2bf(v.x) | ((unsigned int)f2bf(v.y) << 16);
            ((unsigned int*)xbf)[i] = p;
        }
    } else {
        int w = (bid - xblocks) * 256 + threadIdx.x;
        if (w < 40960) {
            const float* src;
            int local;
            if      (w < 8192)  { src = p0; local = w; }
            else if (w < 16384) { src = p1; local = w - 8192; }
            else if (w < 24576) { src = p2; local = w - 16384; }
            else if (w < 32768) { src = p3; local = w - 24576; }
            else if (w < 36864) { src = p4; local = w - 32768; }
            else                { src = p5; local = w - 36864; }
            float2 v = ((const float2*)src)[local];
            unsigned int p = (unsigned int)f2bf(v.x) | ((unsigned int)f2bf(v.y) << 16);
            ((unsigned int*)wbf)[w] = p;
        }
    }
}

// ---------------- MFMA GEMM (unchanged) ----------------

__global__ __launch_bounds__(256) void gemm_mfma_kernel(const unsigned short* __restrict__ H,
                                                        const unsigned short* __restrict__ Wl,
                                                        const unsigned short* __restrict__ Wr,
                                                        unsigned short* __restrict__ C,
                                                        int N, int ldC) {
    int wave = threadIdx.x >> 6;
    int lane = threadIdx.x & 63;
    int l15 = lane & 15, quad = lane >> 4;
    int y = blockIdx.y, half = gridDim.y >> 1;
    const unsigned short* W = (y < half) ? Wl : Wr;
    int wrow0 = (y < half ? y : y - half) * 64;
    int col0 = y * 64;
    int m0 = blockIdx.x * 128 + wave * 32;

    int r0 = m0 + l15;      if (r0 > N - 1) r0 = N - 1;
    int r1 = m0 + 16 + l15; if (r1 > N - 1) r1 = N - 1;
    const bf16x8* A0 = (const bf16x8*)(H + (size_t)r0 * 128);
    const bf16x8* A1 = (const bf16x8*)(H + (size_t)r1 * 128);

    f32x4 acc[2][4] = {};
#pragma unroll
    for (int ks = 0; ks < 4; ++ks) {
        int vidx = ks * 4 + quad;
        bf16x8 a0 = A0[vidx];
        bf16x8 a1 = A1[vidx];
#pragma unroll
        for (int j = 0; j < 4; ++j) {
            const bf16x8* B = (const bf16x8*)(W + (size_t)(wrow0 + j * 16 + l15) * 128);
            bf16x8 b = B[vidx];
            acc[0][j] = __builtin_amdgcn_mfma_f32_16x16x32_bf16(a0, b, acc[0][j], 0, 0, 0);
            acc[1][j] = __builtin_amdgcn_mfma_f32_16x16x32_bf16(a1, b, acc[1][j], 0, 0, 0);
        }
    }

#pragma unroll
    for (int i = 0; i < 2; ++i)
#pragma unroll
        for (int j = 0; j < 4; ++j)
#pragma unroll
            for (int r = 0; r < 4; ++r) {
                int row = m0 + i * 16 + quad * 4 + r;
                if (row < N) {
                    int col = col0 + j * 16 + l15;
                    C[(size_t)row * ldC + col] = f2bf(acc[i][j][r]);
                }
            }
}

// ---------------- Aggregation (layers 0,1): wave/node, batched gathers ----------------

__global__ __launch_bounds__(256) void agg_relu_kernel(const unsigned short* __restrict__ C,
                                                       const int* __restrict__ row_ptr,
                                                       const int* __restrict__ adj,
                                                       const float* __restrict__ bias,
                                                       unsigned short* __restrict__ hout, int N) {
    int node = (int)((blockIdx.x * blockDim.x + threadIdx.x) >> 6);
    int lane = threadIdx.x & 63;
    if (node >= N) return;
    int beg = row_ptr[node], end = row_ptr[node + 1];
    float sx0 = 0.f, sy0 = 0.f, sx1 = 0.f, sy1 = 0.f;
    float sx2 = 0.f, sy2 = 0.f, sx3 = 0.f, sy3 = 0.f;

    int e = beg;
    while (e < end) {
        int cnt = end - e; if (cnt > 64) cnt = 64;
        int ll = lane; if (ll > cnt - 1) ll = cnt - 1;
        int myidx = adj[e + ll];

        int i = 0;
        for (; i + 8 <= cnt; i += 8) {
            int s0 = __shfl(myidx, i + 0), s1 = __shfl(myidx, i + 1);
            int s2 = __shfl(myidx, i + 2), s3 = __shfl(myidx, i + 3);
            int s4 = __shfl(myidx, i + 4), s5 = __shfl(myidx, i + 5);
            int s6 = __shfl(myidx, i + 6), s7 = __shfl(myidx, i + 7);
            unsigned int v0 = ((const unsigned int*)(C + (size_t)s0 * 256))[lane];
            unsigned int v1 = ((const unsigned int*)(C + (size_t)s1 * 256))[lane];
            unsigned int v2 = ((const unsigned int*)(C + (size_t)s2 * 256))[lane];
            unsigned int v3 = ((const unsigned int*)(C + (size_t)s3 * 256))[lane];
            unsigned int v4 = ((const unsigned int*)(C + (size_t)s4 * 256))[lane];
            unsigned int v5 = ((const unsigned int*)(C + (size_t)s5 * 256))[lane];
            unsigned int v6 = ((const unsigned int*)(C + (size_t)s6 * 256))[lane];
            unsigned int v7 = ((const unsigned int*)(C + (size_t)s7 * 256))[lane];
            sx0 += bf2f(v0 & 0xffffu); sy0 += bf2f(v0 >> 16);
            sx1 += bf2f(v1 & 0xffffu); sy1 += bf2f(v1 >> 16);
            sx2 += bf2f(v2 & 0xffffu); sy2 += bf2f(v2 >> 16);
            sx3 += bf2f(v3 & 0xffffu); sy3 += bf2f(v3 >> 16);
            sx0 += bf2f(v4 & 0xffffu); sy0 += bf2f(v4 >> 16);
            sx1 += bf2f(v5 & 0xffffu); sy1 += bf2f(v5 >> 16);
            sx2 += bf2f(v6 & 0xffffu); sy2 += bf2f(v6 >> 16);
            sx3 += bf2f(v7 & 0xffffu); sy3 += bf2f(v7 >> 16);
        }
        if (i < cnt) {
            int rem = cnt - i, c1 = cnt - 1;
            int t0 = i, t1 = i + 1, t2 = i + 2, t3 = i + 3;
            int t4 = i + 4, t5 = i + 5, t6 = i + 6, t7 = i + 7;
            int s0 = __shfl(myidx, t0 > c1 ? c1 : t0), s1 = __shfl(myidx, t1 > c1 ? c1 : t1);
            int s2 = __shfl(myidx, t2 > c1 ? c1 : t2), s3 = __shfl(myidx, t3 > c1 ? c1 : t3);
            int s4 = __shfl(myidx, t4 > c1 ? c1 : t4), s5 = __shfl(myidx, t5 > c1 ? c1 : t5);
            int s6 = __shfl(myidx, t6 > c1 ? c1 : t6), s7 = __shfl(myidx, t7 > c1 ? c1 : t7);
            unsigned int v0 = ((const unsigned int*)(C + (size_t)s0 * 256))[lane];
            unsigned int v1 = ((const unsigned int*)(C + (size_t)s1 * 256))[lane];
            unsigned int v2 = ((const unsigned int*)(C + (size_t)s2 * 256))[lane];
            unsigned int v3 = ((const unsigned int*)(C + (size_t)s3 * 256))[lane];
            unsigned int v4 = ((const unsigned int*)(C + (size_t)s4 * 256))[lane];
            unsigned int v5 = ((const unsigned int*)(C + (size_t)s5 * 256))[lane];
            unsigned int v6 = ((const unsigned int*)(C + (size_t)s6 * 256))[lane];
            unsigned int v7 = ((const unsigned int*)(C + (size_t)s7 * 256))[lane];
            float m1 = rem > 1 ? 1.f : 0.f, m2 = rem > 2 ? 1.f : 0.f, m3 = rem > 3 ? 1.f : 0.f;
            float m4 = rem > 4 ? 1.f : 0.f, m5 = rem > 5 ? 1.f : 0.f, m6 = rem > 6 ? 1.f : 0.f;
            float m7 = rem > 7 ? 1.f : 0.f;
            sx0 += bf2f(v0 & 0xffffu);      sy0 += bf2f(v0 >> 16);
            sx1 += m1 * bf2f(v1 & 0xffffu); sy1 += m1 * bf2f(v1 >> 16);
            sx2 += m2 * bf2f(v2 & 0xffffu); sy2 += m2 * bf2f(v2 >> 16);
            sx3 += m3 * bf2f(v3 & 0xffffu); sy3 += m3 * bf2f(v3 >> 16);
            sx0 += m4 * bf2f(v4 & 0xffffu); sy0 += m4 * bf2f(v4 >> 16);
            sx1 += m5 * bf2f(v5 & 0xffffu); sy1 += m5 * bf2f(v5 >> 16);
            sx2 += m6 * bf2f(v6 & 0xffffu); sy2 += m6 * bf2f(v6 >> 16);
            sx3 += m7 * bf2f(v7 & 0xffffu); sy3 += m7 * bf2f(v7 >> 16);
        }
        e += cnt;
    }

    float sx = (sx0 + sx1) + (sx2 + sx3);
    float sy = (sy0 + sy1) + (sy2 + sy3);
    int deg = end - beg;
    float inv = 1.0f / (float)(deg > 1 ? deg : 1);
    float2 bb = ((const float2*)bias)[lane];
    unsigned int rv = ((const unsigned int*)(C + (size_t)node * 256))[64 + lane];
    float ox = fmaxf(sx * inv + bb.x + bf2f(rv & 0xffffu), 0.f);
    float oy = fmaxf(sy * inv + bb.y + bf2f(rv >> 16), 0.f);
    unsigned int p = (unsigned int)f2bf(ox) | ((unsigned int)f2bf(oy) << 16);
    ((unsigned int*)(hout + (size_t)node * 128))[lane] = p;
}

// ---------------- Final layer: batched gathers + fused log_softmax ----------------

__global__ __launch_bounds__(256) void final_kernel(const unsigned short* __restrict__ C,
                                                    const int* __restrict__ row_ptr,
                                                    const int* __restrict__ adj,
                                                    const float* __restrict__ bias,
                                                    float* __restrict__ out, int N) {
    int node = (int)((blockIdx.x * blockDim.x + threadIdx.x) >> 6);
    int lane = threadIdx.x & 63;
    if (node >= N) return;
    int beg = row_ptr[node], end = row_ptr[node + 1];
    float a0 = 0.f, a1 = 0.f, a2 = 0.f, a3 = 0.f;

    int e = beg;
    while (e < end) {
        int cnt = end - e; if (cnt > 64) cnt = 64;
        int ll = lane; if (ll > cnt - 1) ll = cnt - 1;
        int myidx = adj[e + ll];

        int i = 0;
        for (; i + 8 <= cnt; i += 8) {
            int s0 = __shfl(myidx, i + 0), s1 = __shfl(myidx, i + 1);
            int s2 = __shfl(myidx, i + 2), s3 = __shfl(myidx, i + 3);
            int s4 = __shfl(myidx, i + 4), s5 = __shfl(myidx, i + 5);
            int s6 = __shfl(myidx, i + 6), s7 = __shfl(myidx, i + 7);
            float v0 = bf2f((unsigned int)C[(size_t)s0 * 128 + lane]);
            float v1 = bf2f((unsigned int)C[(size_t)s1 * 128 + lane]);
            float v2 = bf2f((unsigned int)C[(size_t)s2 * 128 + lane]);
            float v3 = bf2f((unsigned int)C[(size_t)s3 * 128 + lane]);
            float v4 = bf2f((unsigned int)C[(size_t)s4 * 128 + lane]);
            float v5 = bf2f((unsigned int)C[(size_t)s5 * 128 + lane]);
            float v6 = bf2f((unsigned int)C[(size_t)s6 * 128 + lane]);
            float v7 = bf2f((unsigned int)C[(size_t)s7 * 128 + lane]);
            a0 += v0 + v4; a1 += v1 + v5; a2 += v2 + v6; a3 += v3 + v7;
        }
        if (i < cnt) {
            int rem = cnt - i, c1 = cnt - 1;
            int t;
            t = i + 0; int s0 = __shfl(myidx, t > c1 ? c1 : t);
            t = i + 1; int s1 = __shfl(myidx, t > c1 ? c1 : t);
            t = i + 2; int s2 = __shfl(myidx, t > c1 ? c1 : t);
            t = i + 3; int s3 = __shfl(myidx, t > c1 ? c1 : t);
            t = i + 4; int s4 = __shfl(myidx, t > c1 ? c1 : t);
            t = i + 5; int s5 = __shfl(myidx, t > c1 ? c1 : t);
            t = i + 6; int s6 = __shfl(myidx, t > c1 ? c1 : t);
            t = i + 7; int s7 = __shfl(myidx, t > c1 ? c1 : t);
            float v0 = bf2f((unsigned int)C[(size_t)s0 * 128 + lane]);
            float v1 = bf2f((unsigned int)C[(size_t)s1 * 128 + lane]);
            float v2 = bf2f((unsigned int)C[(size_t)s2 * 128 + lane]);
            float v3 = bf2f((unsigned int)C[(size_t)s3 * 128 + lane]);
            float v4 = bf2f((unsigned int)C[(size_t)s4 * 128 + lane]);
            float v5 = bf2f((unsigned int)C[(size_t)s5 * 128 + lane]);
            float v6 = bf2f((unsigned int)C[(size_t)s6 * 128 + lane]);
            float v7 = bf2f((unsigned int)C[(size_t)s7 * 128 + lane]);
            float m1 = rem > 1 ? 1.f : 0.f, m2 = rem > 2 ? 1.f : 0.f, m3 = rem > 3 ? 1.f : 0.f;
            float m4 = rem > 4 ? 1.f : 0.f, m5 = rem > 5 ? 1.f : 0.f, m6 = rem > 6 ? 1.f : 0.f;
            float m7 = rem > 7 ? 1.f : 0.f;
            a0 += v0 + m4 * v4; a1 += m1 * v1 + m5 * v5;
            a2 += m2 * v2 + m6 * v6; a3 += m3 * v3 + m7 * v7;
        }
        e += cnt;
    }

    float sum = (a0 + a1) + (a2 + a3);
    int deg = end - beg;
    float inv = 1.0f / (float)(deg > 1 ? deg : 1);
    float u = sum * inv + bias[lane] + bf2f((unsigned int)C[(size_t)node * 128 + 64 + lane]);

    float m = u;
#pragma unroll
    for (int off = 32; off > 0; off >>= 1) m = fmaxf(m, __shfl_xor(m, off));
    float ex = __expf(u - m);
    float se = ex;
#pragma unroll
    for (int off = 32; off > 0; off >>= 1) se += __shfl_xor(se, off);
    out[(size_t)node * 64 + lane] = (u - m) - __logf(se);
}

// ---------------- Launch ----------------

extern "C" void kernel_launch(void* const* d_in, const int* in_sizes, int n_in,
                              void* d_out, int out_size, void* d_ws, size_t ws_size,
                              hipStream_t stream) {
    const float* x   = (const float*)d_in[0];
    const int*   ei  = (const int*)d_in[1];
    const float* Wl0 = (const float*)d_in[2];
    const float* bl0 = (const float*)d_in[3];
    const float* Wr0 = (const float*)d_in[4];
    const float* Wl1 = (const float*)d_in[5];
    const float* bl1 = (const float*)d_in[6];
    const float* Wr1 = (const float*)d_in[7];
    const float* Wl2 = (const float*)d_in[8];
    const float* bl2 = (const float*)d_in[9];
    const float* Wr2 = (const float*)d_in[10];
    float* out = (float*)d_out;

    const int N  = in_sizes[0] / 128;   // 50000
    const int E  = in_sizes[1] / 2;     // 800000
    const int NB = (N + NPB - 1) / NPB; // 391 buckets

    char* ws = (char*)d_ws;
    auto alloc = [&](size_t bytes) {
        char* p = ws;
        ws += (bytes + 255) & ~(size_t)255;
        return p;
    };
    int*   row_ptr    = (int*)alloc((size_t)(N + 1) * 4);
    int*   adj        = (int*)alloc((size_t)E * 4);
    int*   gcnt       = (int*)alloc((size_t)NB * CPAD * 4);  // 64B-padded counters
    int*   bucketBase = (int*)alloc((size_t)NB * 4);
    unsigned int* staging = (unsigned int*)alloc((size_t)NB * BCAP * 4);
    unsigned short* xbf = (unsigned short*)alloc((size_t)N * 128 * 2);
    unsigned short* wbf = (unsigned short*)alloc((size_t)81920 * 2);
    unsigned short* C   = (unsigned short*)alloc((size_t)N * 256 * 2);
    unsigned short* hA  = (unsigned short*)alloc((size_t)N * 128 * 2);
    unsigned short* hB  = (unsigned short*)alloc((size_t)N * 128 * 2);

    const int* dstp = ei;       // edge_index row 0 = dst
    const int* srcp = ei + E;   // edge_index row 1 = src

    // CSR build (block-staged distribute -> scan -> per-bucket build)
    hipMemsetAsync(gcnt, 0, (size_t)NB * CPAD * 4, stream);
    int distBlocks = (E + EPB - 1) / EPB;   // 98
    distribute_kernel<<<distBlocks, 256, 0, stream>>>(dstp, srcp, gcnt, staging, E, NB);
    bucket_scan_kernel<<<1, 512, 0, stream>>>(gcnt, bucketBase, NB, row_ptr + N);
    build_kernel<<<NB, 256, 0, stream>>>(staging, gcnt, bucketBase, row_ptr, adj, N);

    // fused casts
    int xpairs = N * 64;
    int castBlocks = (xpairs + 255) / 256 + 160;
    cast_all_kernel<<<castBlocks, 256, 0, stream>>>(x, Wl0, Wr0, Wl1, Wr1, Wl2, Wr2,
                                                    xbf, wbf, xpairs);
    unsigned short* wl0 = wbf;
    unsigned short* wr0 = wbf + 16384;
    unsigned short* wl1 = wbf + 32768;
    unsigned short* wr1 = wbf + 49152;
    unsigned short* wl2 = wbf + 65536;
    unsigned short* wr2 = wbf + 73728;

    dim3 blk(256);
    int gemmRows = (N + 127) / 128;
    int aggBlocks = (N * 64 + 255) / 256;

    // Layer 0
    gemm_mfma_kernel<<<dim3(gemmRows, 4), blk, 0, stream>>>(xbf, wl0, wr0, C, N, 256);
    agg_relu_kernel<<<aggBlocks, blk, 0, stream>>>(C, row_ptr, adj, bl0, hA, N);
    // Layer 1
    gemm_mfma_kernel<<<dim3(gemmRows, 4), blk, 0, stream>>>(hA, wl1, wr1, C, N, 256);
    agg_relu_kernel<<<aggBlocks, blk, 0, stream>>>(C, row_ptr, adj, bl1, hB, N);
    // Layer 2 + log_softmax
    gemm_mfma_kernel<<<dim3(gemmRows, 2), blk, 0, stream>>>(hB, wl2, wr2, C, N, 128);
    final_kernel<<<aggBlocks, blk, 0, stream>>>(C, row_ptr, adj, bl2, out, N);
}